// Round 1
// baseline (230.980 us; speedup 1.0000x reference)
//
#include <hip/hip_runtime.h>

typedef unsigned short u16;
typedef __attribute__((ext_vector_type(8))) short short8;   // 8 bf16 = 4 VGPRs
typedef __attribute__((ext_vector_type(4))) float floatx4;
typedef __attribute__((ext_vector_type(4))) unsigned uintx4;

#define MFMA16(a, b, c) __builtin_amdgcn_mfma_f32_16x16x32_bf16(a, b, c, 0, 0, 0)

__device__ inline u16 bf16rn(float x) {
    unsigned u = __float_as_uint(x);
    u += 0x7fffu + ((u >> 16) & 1u);
    return (u16)(u >> 16);
}
__device__ inline float bf16tof(u16 h) { return __uint_as_float(((unsigned)h) << 16); }
__device__ inline short8 ld8(const u16* p) { return *(const short8*)p; }
// pack two f32 into one u32 of 2 bf16 (truncation): low16=trunc(a), high16=trunc(b)
__device__ inline unsigned pack2(float a, float b) {
    return __builtin_amdgcn_perm(__float_as_uint(b), __float_as_uint(a), 0x07060302u);
}

// ---------------------------------------------------------------------------
// Consolidated precompute: E transpose (blk<32), rel K rows (blk 32..63),
// conv14 weight transpose w2[g][ic][oc*9+kk] (blk 64..71).
__global__ __launch_bounds__(256) void k_ecvt2(const float* __restrict__ E,
                                               const float* __restrict__ rel,
                                               const float* __restrict__ w,
                                               u16* __restrict__ EhT,
                                               u16* __restrict__ ElT,
                                               u16* __restrict__ Kh,
                                               u16* __restrict__ Kl,
                                               u16* __restrict__ KhT,
                                               u16* __restrict__ KlT,
                                               float* __restrict__ w2) {
    int blk = blockIdx.x, tid = threadIdx.x;
    if (blk < 32) {                       // E transpose + hi/lo
        __shared__ float ep[196 * 65];
        int m = blk;
        const float* eb = E + (size_t)m * 12544;
        for (int t = tid; t < 12544; t += 256) {
            int p = t >> 6, h = t & 63;
            ep[p * 65 + h] = eb[t];
        }
        __syncthreads();
        for (int t = tid; t < 64 * 224; t += 256) {
            int h = t / 224, p = t % 224;
            float v = (p < 196) ? ep[p * 65 + h] : 0.f;
            u16 hi = bf16rn(v);
            u16 lo = bf16rn(v - bf16tof(hi));
            EhT[(size_t)m * 14336 + t] = hi;
            ElT[(size_t)m * 14336 + t] = lo;
        }
    } else if (blk < 64) {                // rel rows -> K arrays (i 2048..2111)
        int b = blk - 32;
        size_t bK = (size_t)b * 2112;
        size_t bT = (size_t)b * 33792;
#pragma unroll
        for (int k = 0; k < 4; ++k) {
            int idx = tid + k * 256;      // [0,1024)
            int row = idx >> 4, e = idx & 15;
            int i = 2048 + row;
            float v = (row < 49) ? rel[e * 49 + row] : 0.f;
            u16 h = bf16rn(v);
            u16 l = bf16rn(v - bf16tof(h));
            Kh[(bK + i) * 16 + e] = h;
            Kl[(bK + i) * 16 + e] = l;
            KhT[bT + (size_t)e * 2112 + i] = h;
            KlT[bT + (size_t)e * 2112 + i] = l;
        }
    } else {                              // conv14 weight transpose, 4 g per block
        int g0 = (blk - 64) * 4;
        for (int t = tid; t < 4 * 2304; t += 256) {
            int g = g0 + t / 2304, r = t % 2304;
            int oc = r / 144, rr = r % 144;
            w2[(size_t)g * 2304 + (rr / 9) * 144 + oc * 9 + (rr % 9)] =
                w[(size_t)g * 2304 + r];
        }
    }
}

// ---------------------------------------------------------------------------
// Grouped 3x3 conv 14x14, oc-split x2, transposed weights (contiguous s_load).
__global__ __launch_bounds__(256) void k_conv14(const float* __restrict__ pose,
                                                const float* __restrict__ w2,
                                                float* __restrict__ out) {
    int blk = blockIdx.x;          // (b*32+g)*2 + oh
    int oh = blk & 1, bg = blk >> 1;
    int tid = threadIdx.x;
    __shared__ float patch[16 * 256];
#pragma unroll
    for (int k = 0; k < 16; ++k) patch[k * 256 + tid] = 0.f;
    __syncthreads();
    const float* pin = pose + (size_t)bg * 3136;
    for (int t = tid; t < 3136; t += 256) {
        int p = t >> 4, ic = t & 15;
        int y = p / 14, x = p % 14;
        patch[ic * 256 + (y + 1) * 16 + (x + 1)] = pin[t];
    }
    __syncthreads();
    int g = bg & 31;
    const float* wg = w2 + (size_t)g * 2304 + oh * 72;
    float* po = out + (size_t)bg * 3136 + oh * 8 * 196;
    if (tid < 196) {
        int y = tid / 14, x = tid % 14;
        int base = (y + 1) * 16 + (x + 1);
        float acc[8];
#pragma unroll
        for (int oc = 0; oc < 8; ++oc) acc[oc] = 0.f;
        for (int ic = 0; ic < 16; ++ic) {
            const float* pr = patch + ic * 256 + base;
            float win[9];
#pragma unroll
            for (int ky = 0; ky < 3; ++ky)
#pragma unroll
                for (int kx = 0; kx < 3; ++kx)
                    win[ky * 3 + kx] = pr[(ky - 1) * 16 + (kx - 1)];
            const float* wi = wg + ic * 144;
#pragma unroll
            for (int oc = 0; oc < 8; ++oc)
#pragma unroll
                for (int kk = 0; kk < 9; ++kk)
                    acc[oc] += win[kk] * wi[oc * 9 + kk];
        }
#pragma unroll
        for (int oc = 0; oc < 8; ++oc) po[oc * 196 + tid] = acc[oc];
    }
}

// ---------------------------------------------------------------------------
// Grouped 3x3 conv 7x7, oc-split x2. mode=1: permuted pose input; mode=0: in+in2.
__global__ __launch_bounds__(64) void k_conv7(const float* __restrict__ in,
                                              const float* __restrict__ in2,
                                              const float* __restrict__ w,
                                              float* __restrict__ out, int mode) {
    int blk = blockIdx.x;          // (b*32+g)*2 + oh
    int oh = blk & 1, bg = blk >> 1;
    int tid = threadIdx.x;
    __shared__ float patch[16 * 144];
    for (int t = tid; t < 16 * 144; t += 64) patch[t] = 0.f;
    __syncthreads();
    const float* pin = in + (size_t)bg * 784;
    if (mode == 1) {
        for (int t = tid; t < 784; t += 64) {
            int p = t >> 4, ic = t & 15;
            int y = p / 7, x = p % 7;
            patch[ic * 144 + (y + 1) * 16 + (x + 1)] = pin[t];
        }
    } else {
        const float* pin2 = in2 + (size_t)bg * 784;
        for (int t = tid; t < 784; t += 64) {
            int ic = t / 49, p = t % 49;
            int y = p / 7, x = p % 7;
            patch[ic * 144 + (y + 1) * 16 + (x + 1)] = pin[t] + pin2[t];
        }
    }
    __syncthreads();
    int g = bg & 31;
    const float* wg = w + (size_t)g * 2304 + (size_t)oh * 8 * 144;
    float* po = out + (size_t)bg * 784 + (size_t)oh * 8 * 49;
    if (tid < 49) {
        int y = tid / 7, x = tid % 7;
        int base = (y + 1) * 16 + (x + 1);
        float acc[8];
#pragma unroll
        for (int oc = 0; oc < 8; ++oc) acc[oc] = 0.f;
        for (int ic = 0; ic < 16; ++ic) {
            const float* pr = patch + ic * 144 + base;
            float win[9];
#pragma unroll
            for (int ky = 0; ky < 3; ++ky)
#pragma unroll
                for (int kx = 0; kx < 3; ++kx)
                    win[ky * 3 + kx] = pr[(ky - 1) * 16 + (kx - 1)];
            const float* wi = wg + ic * 9;
#pragma unroll
            for (int oc = 0; oc < 8; ++oc)
#pragma unroll
                for (int kk = 0; kk < 9; ++kk)
                    acc[oc] += win[kk] * wi[oc * 144 + kk];
        }
#pragma unroll
        for (int oc = 0; oc < 8; ++oc) po[oc * 49 + tid] = acc[oc];
    }
}

// ---------------------------------------------------------------------------
// MFMA key projection: per (b,m): D[16e x 64h] = cp[16e x 196p] * E[m][196p x 64h].
__global__ __launch_bounds__(256) void k_kproj2(const float* __restrict__ cpconv,
                                                const u16* __restrict__ EhT,
                                                const u16* __restrict__ ElT,
                                                u16* __restrict__ Kh,
                                                u16* __restrict__ Kl,
                                                u16* __restrict__ KhT,
                                                u16* __restrict__ KlT) {
    int blk = blockIdx.x;           // b*32 + m
    int b = blk >> 5, m = blk & 31;
    int wave = threadIdx.x >> 6, lane = threadIdx.x & 63;
    int ht = wave;                  // h-tile 0..3
    int n = lane & 15, quad = lane >> 4;

    const float* arow = cpconv + ((size_t)b * 512 + (size_t)n * 32 + m) * 196;
    const u16* bhrow = EhT + ((size_t)m * 64 + ht * 16 + n) * 224;
    const u16* blrow = ElT + ((size_t)m * 64 + ht * 16 + n) * 224;

    floatx4 c = {0.f, 0.f, 0.f, 0.f};
#pragma unroll
    for (int pc = 0; pc < 7; ++pc) {
        int p0 = pc * 32 + quad * 8;
        float av[8];
        if (p0 <= 188) {
            float4 x = *(const float4*)(arow + p0);
            float4 y = *(const float4*)(arow + p0 + 4);
            av[0]=x.x; av[1]=x.y; av[2]=x.z; av[3]=x.w;
            av[4]=y.x; av[5]=y.y; av[6]=y.z; av[7]=y.w;
        } else {
#pragma unroll
            for (int k2 = 0; k2 < 8; ++k2) av[k2] = (p0 + k2 < 196) ? arow[p0 + k2] : 0.f;
        }
        short8 ah, al;
#pragma unroll
        for (int k2 = 0; k2 < 8; ++k2) {
            u16 h = bf16rn(av[k2]);
            ah[k2] = (short)h;
            al[k2] = (short)bf16rn(av[k2] - bf16tof(h));
        }
        short8 bh = ld8(bhrow + pc * 32 + quad * 8);
        short8 bl = ld8(blrow + pc * 32 + quad * 8);
        c = MFMA16(ah, bh, c);
        c = MFMA16(ah, bl, c);
        c = MFMA16(al, bh, c);
    }
    int i = m * 64 + ht * 16 + n;
    size_t bK = (size_t)b * 2112;
    size_t bT = (size_t)b * 33792;
    u16 h[4], l[4];
#pragma unroll
    for (int r = 0; r < 4; ++r) {
        h[r] = bf16rn(c[r]);
        l[r] = bf16rn(c[r] - bf16tof(h[r]));
    }
    *(uint2*)(Kh + (bK + i) * 16 + quad * 4) =
        make_uint2((unsigned)h[0] | ((unsigned)h[1] << 16), (unsigned)h[2] | ((unsigned)h[3] << 16));
    *(uint2*)(Kl + (bK + i) * 16 + quad * 4) =
        make_uint2((unsigned)l[0] | ((unsigned)l[1] << 16), (unsigned)l[2] | ((unsigned)l[3] << 16));
#pragma unroll
    for (int r = 0; r < 4; ++r) {
        KhT[bT + (size_t)(quad * 4 + r) * 2112 + i] = h[r];
        KlT[bT + (size_t)(quad * 4 + r) * 2112 + i] = l[r];
    }
}

// ---------------------------------------------------------------------------
// Q conversion (x0.25, hi/lo bf16).
__global__ __launch_bounds__(256) void k_cvt(const float* __restrict__ qconv,
                                             u16* __restrict__ Qp) {
    int gid = blockIdx.x * 256 + threadIdx.x;
    const float4* q4 = (const float4*)(qconv + (size_t)gid * 16);
    float4 t0 = q4[0], t1 = q4[1], t2 = q4[2], t3 = q4[3];
    float v[16] = {t0.x,t0.y,t0.z,t0.w, t1.x,t1.y,t1.z,t1.w,
                   t2.x,t2.y,t2.z,t2.w, t3.x,t3.y,t3.z,t3.w};
    unsigned hw[8], lw[8];
#pragma unroll
    for (int t = 0; t < 8; ++t) {
        float x0 = v[2*t] * 0.25f, x1 = v[2*t+1] * 0.25f;
        u16 h0 = bf16rn(x0), h1 = bf16rn(x1);
        u16 l0 = bf16rn(x0 - bf16tof(h0)), l1 = bf16rn(x1 - bf16tof(h1));
        hw[t] = (unsigned)h0 | ((unsigned)h1 << 16);
        lw[t] = (unsigned)l0 | ((unsigned)l1 << 16);
    }
    uint4* r4 = (uint4*)(Qp + (size_t)gid * 32);
    r4[0] = make_uint4(hw[0], hw[1], hw[2], hw[3]);
    r4[1] = make_uint4(hw[4], hw[5], hw[6], hw[7]);
    r4[2] = make_uint4(lw[0], lw[1], lw[2], lw[3]);
    r4[3] = make_uint4(lw[4], lw[5], lw[6], lw[7]);
}

// ---------------------------------------------------------------------------
// Column denominators: barrier-free, K frags in registers, Q streamed from L2.
__global__ __launch_bounds__(256) void k_stats4(const u16* __restrict__ Qp,
                                                const u16* __restrict__ Kh,
                                                const u16* __restrict__ Kl,
                                                float* __restrict__ dpart) {
    int blk = blockIdx.x;                   // b*34 + jh*17 + tb
    int b = blk / 34; int rem = blk % 34; int jh = rem / 17; int tb = rem % 17;
    int wave = threadIdx.x >> 6, lane = threadIdx.x & 63;
    int it2 = tb * 4 + wave;                // i-pair 0..67
    if (it2 >= 66) return;
    int ibase = it2 * 32;
    int n = lane & 15, quad = lane >> 4;
    size_t bK = (size_t)b * 2112;
    const u16* kb = Kh + (bK + ibase + n) * 16 + (quad & 1) * 8;
    const u16* lb = Kl + (bK + ibase + n) * 16 + (quad & 1) * 8;
    short8 bh0 = ld8(kb), bh1 = ld8(kb + 256);
    short8 bl0 = ld8(lb), bl1 = ld8(lb + 256);
    const u16* qb = Qp + (size_t)b * 50176 + (size_t)jh * 49 * 512 + n * 32 + quad * 8;
    floatx4 d0 = {0.f,0.f,0.f,0.f}, d1 = {0.f,0.f,0.f,0.f};
    short8 a0 = ld8(qb), a1 = ld8(qb + 512);
    for (int c = 0; c < 49; ++c) {
        short8 a2 = (c + 2 < 49) ? ld8(qb + (size_t)(c + 2) * 512) : a0;
        floatx4 s0 = {0.f,0.f,0.f,0.f}, s1 = {0.f,0.f,0.f,0.f};
        s0 = MFMA16(a0, bh0, s0);
        s0 = MFMA16(a0, bl0, s0);
        s1 = MFMA16(a0, bh1, s1);
        s1 = MFMA16(a0, bl1, s1);
        d0.x += __expf(s0.x); d0.y += __expf(s0.y);
        d0.z += __expf(s0.z); d0.w += __expf(s0.w);
        d1.x += __expf(s1.x); d1.y += __expf(s1.y);
        d1.z += __expf(s1.z); d1.w += __expf(s1.w);
        a0 = a1; a1 = a2;
    }
    float t0 = d0.x + d0.y + d0.z + d0.w;
    float t1 = d1.x + d1.y + d1.z + d1.w;
    t0 += __shfl_xor(t0, 16); t0 += __shfl_xor(t0, 32);
    t1 += __shfl_xor(t1, 16); t1 += __shfl_xor(t1, 32);
    if (quad == 0) {
        dpart[(size_t)jh * 67584 + bK + ibase + n]      = t0;
        dpart[(size_t)jh * 67584 + bK + ibase + 16 + n] = t1;
    }
}

// ---------------------------------------------------------------------------
// Scale V rows by 1/denom in place: Vt[e][i] = (KhT+KlT)[e][i] / d[i], hi/lo split.
__global__ __launch_bounds__(256) void k_vscale(const float* __restrict__ dpart,
                                                u16* __restrict__ VhT,
                                                u16* __restrict__ VlT) {
    int gid = blockIdx.x * 256 + threadIdx.x;     // 135168 total
    int ic = gid % 264;                           // i-chunk of 8
    int be = gid / 264;                           // b*16 + e
    int b = be >> 4, e = be & 15;
    size_t off = (size_t)b * 33792 + (size_t)e * 2112 + (size_t)ic * 8;
    short8 h8 = ld8(VhT + off);
    short8 l8 = ld8(VlT + off);
    const float* dp = dpart + (size_t)b * 2112 + ic * 8;
    float4 da0 = *(const float4*)dp;
    float4 da1 = *(const float4*)(dp + 4);
    float4 db0 = *(const float4*)(dp + 67584);
    float4 db1 = *(const float4*)(dp + 67588);
    float d[8] = {da0.x+db0.x, da0.y+db0.y, da0.z+db0.z, da0.w+db0.w,
                  da1.x+db1.x, da1.y+db1.y, da1.z+db1.z, da1.w+db1.w};
    short8 oh, ol;
#pragma unroll
    for (int k = 0; k < 8; ++k) {
        float v = bf16tof((u16)h8[k]) + bf16tof((u16)l8[k]);
        float sv = v / d[k];
        u16 hh = bf16rn(sv);
        ol[k] = (short)bf16rn(sv - bf16tof(hh));
        oh[k] = (short)hh;
    }
    *(short8*)(VhT + off) = oh;
    *(short8*)(VlT + off) = ol;
}

// ---------------------------------------------------------------------------
// PV v6: swapped QK^T (sT = K*Q) so the W transpose is a register permlane
// network (no w16 LDS round-trip), 1/d pre-folded into V, 2 j-tiles per wave.
__global__ __launch_bounds__(256) void k_pv6(const u16* __restrict__ Qp,
                                             const u16* __restrict__ Kh,
                                             const u16* __restrict__ Kl,
                                             const u16* __restrict__ VhT,
                                             const u16* __restrict__ VlT,
                                             float* __restrict__ opart) {
    __shared__ __align__(16) u16 sH[2][32][16];       // [buf][i][e]  (K hi rows)
    __shared__ __align__(16) u16 sL[2][32][16];       // [buf][i][e]  (K lo rows)
    __shared__ __align__(16) u16 tH[2][16][32];       // [buf][e][i]  (Vt hi)
    __shared__ __align__(16) u16 tL[2][16][32];       // [buf][e][i]  (Vt lo)

    int blk = blockIdx.x;                  // b*26 + jtb*2 + ih
    int b = blk / 26; int rem = blk % 26; int jtb = rem >> 1; int ih = rem & 1;
    int tid = threadIdx.x, wave = tid >> 6, lane = tid & 63;
    int n = lane & 15, quad = lane >> 4, qh = quad & 1;
    int jt0 = (jtb * 4 + wave) * 2;        // 2 j-tiles per wave
    int jc0 = jt0     < 98 ? jt0     : 97;
    int jc1 = jt0 + 1 < 98 ? jt0 + 1 : 97;
    int i0 = ih * 1056;
    size_t bK = (size_t)b * 2112;
    size_t bT = (size_t)b * 33792;

    short8 aq0 = ld8(Qp + ((size_t)b * 1568 + (size_t)jc0 * 16 + n) * 32 + quad * 8);
    short8 aq1 = ld8(Qp + ((size_t)b * 1568 + (size_t)jc1 * 16 + n) * 32 + quad * 8);

    int role = wave, L = lane;
    uint4 sreg;
    auto ldchunk = [&](int c) {
        int i0c = i0 + c * 32;
        if (role == 0)      sreg = *(const uint4*)(Kh  + (bK + i0c + (L >> 1)) * 16 + (L & 1) * 8);
        else if (role == 1) sreg = *(const uint4*)(Kl  + (bK + i0c + (L >> 1)) * 16 + (L & 1) * 8);
        else if (role == 2) sreg = *(const uint4*)(VhT + bT + (size_t)(L >> 2) * 2112 + i0c + (L & 3) * 8);
        else                sreg = *(const uint4*)(VlT + bT + (size_t)(L >> 2) * 2112 + i0c + (L & 3) * 8);
    };
    auto stchunk = [&](int bf) {
        if (role == 0)      *(uint4*)(&sH[bf][L >> 1][(L & 1) * 8]) = sreg;
        else if (role == 1) *(uint4*)(&sL[bf][L >> 1][(L & 1) * 8]) = sreg;
        else if (role == 2) *(uint4*)(&tH[bf][L >> 2][(L & 3) * 8]) = sreg;
        else                *(uint4*)(&tL[bf][L >> 2][(L & 3) * 8]) = sreg;
    };

    floatx4 o0 = {0.f, 0.f, 0.f, 0.f}, o1 = {0.f, 0.f, 0.f, 0.f};

    ldchunk(0); stchunk(0); ldchunk(1);
    __syncthreads();
    for (int c = 0; c < 33; ++c) {
        int cb = c & 1;
        short8 sh0 = ld8(&sH[cb][n][qh * 8]);        // K hi, i-local 0..15 (row n)
        short8 sh1 = ld8(&sH[cb][16 + n][qh * 8]);   // K hi, i-local 16..31
        short8 sl0 = ld8(&sL[cb][n][qh * 8]);
        short8 sl1 = ld8(&sL[cb][16 + n][qh * 8]);
        short8 th  = ld8(&tH[cb][n][quad * 8]);      // Vt hi  B-operand
        short8 tl  = ld8(&tL[cb][n][quad * 8]);

        // ---- j-tile 0: sT = K * Q  -> lane holds sT[i=quad*4+r][j=n]
        {
            floatx4 s0 = {0.f,0.f,0.f,0.f}, s1 = {0.f,0.f,0.f,0.f};
            s0 = MFMA16(sh0, aq0, s0);
            s0 = MFMA16(sl0, aq0, s0);
            s1 = MFMA16(sh1, aq0, s1);
            s1 = MFMA16(sl1, aq0, s1);
            unsigned u00 = pack2(__expf(s0[0]), __expf(s0[1]));  // P(2q)
            unsigned u01 = pack2(__expf(s0[2]), __expf(s0[3]));  // P(2q+1)
            unsigned u10 = pack2(__expf(s1[0]), __expf(s1[1]));  // P(8+2q)
            unsigned u11 = pack2(__expf(s1[2]), __expf(s1[3]));  // P(9+2q)
            asm("v_permlane32_swap_b32 %0, %1" : "+v"(u00), "+v"(u10));
            asm("v_permlane32_swap_b32 %0, %1" : "+v"(u01), "+v"(u11));
            asm("v_permlane16_swap_b32 %0, %1" : "+v"(u00), "+v"(u10));
            asm("v_permlane16_swap_b32 %0, %1" : "+v"(u01), "+v"(u11));
            uintx4 uv = {u00, u01, u10, u11};        // W[j=n][i=8q..8q+7]
            short8 aw = __builtin_bit_cast(short8, uv);
            o0 = MFMA16(aw, th, o0);
            o0 = MFMA16(aw, tl, o0);
        }
        // ---- j-tile 1
        {
            floatx4 s0 = {0.f,0.f,0.f,0.f}, s1 = {0.f,0.f,0.f,0.f};
            s0 = MFMA16(sh0, aq1, s0);
            s0 = MFMA16(sl0, aq1, s0);
            s1 = MFMA16(sh1, aq1, s1);
            s1 = MFMA16(sl1, aq1, s1);
            unsigned u00 = pack2(__expf(s0[0]), __expf(s0[1]));
            unsigned u01 = pack2(__expf(s0[2]), __expf(s0[3]));
            unsigned u10 = pack2(__expf(s1[0]), __expf(s1[1]));
            unsigned u11 = pack2(__expf(s1[2]), __expf(s1[3]));
            asm("v_permlane32_swap_b32 %0, %1" : "+v"(u00), "+v"(u10));
            asm("v_permlane32_swap_b32 %0, %1" : "+v"(u01), "+v"(u11));
            asm("v_permlane16_swap_b32 %0, %1" : "+v"(u00), "+v"(u10));
            asm("v_permlane16_swap_b32 %0, %1" : "+v"(u01), "+v"(u11));
            uintx4 uv = {u00, u01, u10, u11};
            short8 aw = __builtin_bit_cast(short8, uv);
            o1 = MFMA16(aw, th, o1);
            o1 = MFMA16(aw, tl, o1);
        }
        if (c < 32) stchunk((c + 1) & 1);
        if (c < 31) ldchunk(c + 2);
        __syncthreads();
    }
    if (jt0 < 98) {
        float* ob = opart + (size_t)ih * 802816 + ((size_t)b * 1568 + (size_t)jt0 * 16) * 16;
#pragma unroll
        for (int r = 0; r < 4; ++r) ob[(quad * 4 + r) * 16 + n] = o0[r];
    }
    if (jt0 + 1 < 98) {
        float* ob = opart + (size_t)ih * 802816 + ((size_t)b * 1568 + (size_t)(jt0 + 1) * 16) * 16;
#pragma unroll
        for (int r = 0; r < 4; ++r) ob[(quad * 4 + r) * 16 + n] = o1[r];
    }
}

// ---------------------------------------------------------------------------
// LayerNorm over consecutive groups of 16 floats.
__global__ __launch_bounds__(256) void k_ln(const float* __restrict__ x,
                                            const float* __restrict__ gamma,
                                            const float* __restrict__ beta,
                                            float* __restrict__ out, int ngroups) {
    int g = blockIdx.x * 256 + threadIdx.x;
    if (g >= ngroups) return;
    const float4* xp = (const float4*)(x + (size_t)g * 16);
    float4 x0 = xp[0], x1 = xp[1], x2 = xp[2], x3 = xp[3];
    float sum = x0.x + x0.y + x0.z + x0.w + x1.x + x1.y + x1.z + x1.w
              + x2.x + x2.y + x2.z + x2.w + x3.x + x3.y + x3.z + x3.w;
    float mu = sum * 0.0625f;
    float var = 0.f;
    var += (x0.x-mu)*(x0.x-mu) + (x0.y-mu)*(x0.y-mu) + (x0.z-mu)*(x0.z-mu) + (x0.w-mu)*(x0.w-mu);
    var += (x1.x-mu)*(x1.x-mu) + (x1.y-mu)*(x1.y-mu) + (x1.z-mu)*(x1.z-mu) + (x1.w-mu)*(x1.w-mu);
    var += (x2.x-mu)*(x2.x-mu) + (x2.y-mu)*(x2.y-mu) + (x2.z-mu)*(x2.z-mu) + (x2.w-mu)*(x2.w-mu);
    var += (x3.x-mu)*(x3.x-mu) + (x3.y-mu)*(x3.y-mu) + (x3.z-mu)*(x3.z-mu) + (x3.w-mu)*(x3.w-mu);
    float rstd = rsqrtf(var * 0.0625f + 1e-5f);
    const float4* gp = (const float4*)gamma;
    const float4* bp = (const float4*)beta;
    float4 g0 = gp[0], g1 = gp[1], g2 = gp[2], g3 = gp[3];
    float4 be0 = bp[0], be1 = bp[1], be2 = bp[2], be3 = bp[3];
    float4 o0, o1, o2, o3;
    o0.x = (x0.x-mu)*rstd*g0.x + be0.x; o0.y = (x0.y-mu)*rstd*g0.y + be0.y;
    o0.z = (x0.z-mu)*rstd*g0.z + be0.z; o0.w = (x0.w-mu)*rstd*g0.w + be0.w;
    o1.x = (x1.x-mu)*rstd*g1.x + be1.x; o1.y = (x1.y-mu)*rstd*g1.y + be1.y;
    o1.z = (x1.z-mu)*rstd*g1.z + be1.z; o1.w = (x1.w-mu)*rstd*g1.w + be1.w;
    o2.x = (x2.x-mu)*rstd*g2.x + be2.x; o2.y = (x2.y-mu)*rstd*g2.y + be2.y;
    o2.z = (x2.z-mu)*rstd*g2.z + be2.z; o2.w = (x2.w-mu)*rstd*g2.w + be2.w;
    o3.x = (x3.x-mu)*rstd*g3.x + be3.x; o3.y = (x3.y-mu)*rstd*g3.y + be3.y;
    o3.z = (x3.z-mu)*rstd*g3.z + be3.z; o3.w = (x3.w-mu)*rstd*g3.w + be3.w;
    float4* op = (float4*)(out + (size_t)g * 16);
    op[0] = o0; op[1] = o1; op[2] = o2; op[3] = o3;
}

// ---------------------------------------------------------------------------
extern "C" void kernel_launch(void* const* d_in, const int* in_sizes, int n_in,
                              void* d_out, int out_size, void* d_ws, size_t ws_size,
                              hipStream_t stream) {
    const float* current_pose = (const float*)d_in[0];
    const float* next_pose    = (const float*)d_in[1];
    const float* current_w    = (const float*)d_in[2];
    const float* next_w       = (const float*)d_in[3];
    const float* E_proj       = (const float*)d_in[4];
    const float* rel          = (const float*)d_in[5];
    const float* ln_gamma     = (const float*)d_in[6];
    const float* ln_beta      = (const float*)d_in[7];
    float* out = (float*)d_out;
    float* ws  = (float*)d_ws;

    // workspace (floats); cpconv region reused by opart/dpart/conv2 after kproj2
    float* cpconv = ws;                 // 3,211,264
    float* conv2  = ws;                 // alias (written after cpconv last read)
    float* opart  = ws + 802816;        // 2 x 802,816 -> ends 2,408,448
    float* dpart  = ws + 2408448;       // 2 x 67,584 -> ends 2,543,616
    float* qconv  = ws + 3211264;       //   802,816 -> ends 4,014,080
    float* w2     = ws + 4014080;       //    73,728 -> ends 4,087,808
    u16*   ub     = (u16*)(ws + 4087808);
    u16* Qp  = ub;                      // 1,605,632
    u16* Kh  = ub + 1605632;            // 1,081,344
    u16* Kl  = ub + 2686976;
    u16* KhT = ub + 3768320;            // scaled in place to Vt hi by k_vscale
    u16* KlT = ub + 4849664;            // scaled in place to Vt lo
    u16* EhT = ub + 5931008;            // 458,752
    u16* ElT = ub + 6389760;            // ends 6,848,512 (~30.1 MB total)

    k_ecvt2 <<<72,   256, 0, stream>>>(E_proj, rel, current_w, EhT, ElT,
                                       Kh, Kl, KhT, KlT, w2);
    k_conv14<<<2048, 256, 0, stream>>>(current_pose, w2, cpconv);
    k_conv7 <<<2048, 64,  0, stream>>>(next_pose, next_pose, next_w, qconv, 1);
    k_cvt   <<<196,  256, 0, stream>>>(qconv, Qp);
    k_kproj2<<<1024, 256, 0, stream>>>(cpconv, EhT, ElT, Kh, Kl, KhT, KlT);
    k_stats4<<<1088, 256, 0, stream>>>(Qp, Kh, Kl, dpart);
    k_vscale<<<528,  256, 0, stream>>>(dpart, KhT, KlT);
    k_pv6   <<<832,  256, 0, stream>>>(Qp, Kh, Kl, KhT, KlT, opart);
    k_conv7 <<<2048, 64,  0, stream>>>(opart, opart + 802816, next_w, conv2, 0);
    k_ln    <<<196,  256, 0, stream>>>(conv2, ln_gamma, ln_beta, out, 50176);
}

// Round 3
// 225.230 us; speedup vs baseline: 1.0255x; 1.0255x over previous
//
#include <hip/hip_runtime.h>

typedef unsigned short u16;
typedef __attribute__((ext_vector_type(8))) short short8;   // 8 bf16 = 4 VGPRs
typedef __attribute__((ext_vector_type(4))) float floatx4;
typedef __attribute__((ext_vector_type(4))) unsigned uintx4;

#define MFMA16(a, b, c) __builtin_amdgcn_mfma_f32_16x16x32_bf16(a, b, c, 0, 0, 0)

__device__ inline u16 bf16rn(float x) {
    unsigned u = __float_as_uint(x);
    u += 0x7fffu + ((u >> 16) & 1u);
    return (u16)(u >> 16);
}
__device__ inline float bf16tof(u16 h) { return __uint_as_float(((unsigned)h) << 16); }
__device__ inline short8 ld8(const u16* p) { return *(const short8*)p; }
// pack two f32 into one u32 of 2 bf16 (truncation): low16=trunc(a), high16=trunc(b)
__device__ inline unsigned pack2(float a, float b) {
    return __builtin_amdgcn_perm(__float_as_uint(b), __float_as_uint(a), 0x07060302u);
}

// ---------------------------------------------------------------------------
// Consolidated precompute: E transpose (blk<32), rel K rows (blk 32..63),
// conv14 weight transpose w2[g][ic][oc*9+kk] (blk 64..71).
__global__ __launch_bounds__(256) void k_ecvt2(const float* __restrict__ E,
                                               const float* __restrict__ rel,
                                               const float* __restrict__ w,
                                               u16* __restrict__ EhT,
                                               u16* __restrict__ ElT,
                                               u16* __restrict__ Kh,
                                               u16* __restrict__ Kl,
                                               u16* __restrict__ KhT,
                                               u16* __restrict__ KlT,
                                               float* __restrict__ w2) {
    int blk = blockIdx.x, tid = threadIdx.x;
    if (blk < 32) {                       // E transpose + hi/lo
        __shared__ float ep[196 * 65];
        int m = blk;
        const float* eb = E + (size_t)m * 12544;
        for (int t = tid; t < 12544; t += 256) {
            int p = t >> 6, h = t & 63;
            ep[p * 65 + h] = eb[t];
        }
        __syncthreads();
        for (int t = tid; t < 64 * 224; t += 256) {
            int h = t / 224, p = t % 224;
            float v = (p < 196) ? ep[p * 65 + h] : 0.f;
            u16 hi = bf16rn(v);
            u16 lo = bf16rn(v - bf16tof(hi));
            EhT[(size_t)m * 14336 + t] = hi;
            ElT[(size_t)m * 14336 + t] = lo;
        }
    } else if (blk < 64) {                // rel rows -> K arrays (i 2048..2111)
        int b = blk - 32;
        size_t bK = (size_t)b * 2112;
        size_t bT = (size_t)b * 33792;
#pragma unroll
        for (int k = 0; k < 4; ++k) {
            int idx = tid + k * 256;      // [0,1024)
            int row = idx >> 4, e = idx & 15;
            int i = 2048 + row;
            float v = (row < 49) ? rel[e * 49 + row] : 0.f;
            u16 h = bf16rn(v);
            u16 l = bf16rn(v - bf16tof(h));
            Kh[(bK + i) * 16 + e] = h;
            Kl[(bK + i) * 16 + e] = l;
            KhT[bT + (size_t)e * 2112 + i] = h;
            KlT[bT + (size_t)e * 2112 + i] = l;
        }
    } else {                              // conv14 weight transpose, 4 g per block
        int g0 = (blk - 64) * 4;
        for (int t = tid; t < 4 * 2304; t += 256) {
            int g = g0 + t / 2304, r = t % 2304;
            int oc = r / 144, rr = r % 144;
            w2[(size_t)g * 2304 + (rr / 9) * 144 + oc * 9 + (rr % 9)] =
                w[(size_t)g * 2304 + r];
        }
    }
}

// ---------------------------------------------------------------------------
// Grouped 3x3 conv 14x14, oc-split x2, transposed weights (contiguous s_load).
__global__ __launch_bounds__(256) void k_conv14(const float* __restrict__ pose,
                                                const float* __restrict__ w2,
                                                float* __restrict__ out) {
    int blk = blockIdx.x;          // (b*32+g)*2 + oh
    int oh = blk & 1, bg = blk >> 1;
    int tid = threadIdx.x;
    __shared__ float patch[16 * 256];
#pragma unroll
    for (int k = 0; k < 16; ++k) patch[k * 256 + tid] = 0.f;
    __syncthreads();
    const float* pin = pose + (size_t)bg * 3136;
    for (int t = tid; t < 3136; t += 256) {
        int p = t >> 4, ic = t & 15;
        int y = p / 14, x = p % 14;
        patch[ic * 256 + (y + 1) * 16 + (x + 1)] = pin[t];
    }
    __syncthreads();
    int g = bg & 31;
    const float* wg = w2 + (size_t)g * 2304 + oh * 72;
    float* po = out + (size_t)bg * 3136 + oh * 8 * 196;
    if (tid < 196) {
        int y = tid / 14, x = tid % 14;
        int base = (y + 1) * 16 + (x + 1);
        float acc[8];
#pragma unroll
        for (int oc = 0; oc < 8; ++oc) acc[oc] = 0.f;
        for (int ic = 0; ic < 16; ++ic) {
            const float* pr = patch + ic * 256 + base;
            float win[9];
#pragma unroll
            for (int ky = 0; ky < 3; ++ky)
#pragma unroll
                for (int kx = 0; kx < 3; ++kx)
                    win[ky * 3 + kx] = pr[(ky - 1) * 16 + (kx - 1)];
            const float* wi = wg + ic * 144;
#pragma unroll
            for (int oc = 0; oc < 8; ++oc)
#pragma unroll
                for (int kk = 0; kk < 9; ++kk)
                    acc[oc] += win[kk] * wi[oc * 9 + kk];
        }
#pragma unroll
        for (int oc = 0; oc < 8; ++oc) po[oc * 196 + tid] = acc[oc];
    }
}

// ---------------------------------------------------------------------------
// Grouped 3x3 conv 7x7, oc-split x2. mode=1: permuted pose input;
// mode=0: sum of 4 opart partials (in[t], in[t+802816], in2[t], in2[t+802816]).
__global__ __launch_bounds__(64) void k_conv7(const float* __restrict__ in,
                                              const float* __restrict__ in2,
                                              const float* __restrict__ w,
                                              float* __restrict__ out, int mode) {
    int blk = blockIdx.x;          // (b*32+g)*2 + oh
    int oh = blk & 1, bg = blk >> 1;
    int tid = threadIdx.x;
    __shared__ float patch[16 * 144];
    for (int t = tid; t < 16 * 144; t += 64) patch[t] = 0.f;
    __syncthreads();
    const float* pin = in + (size_t)bg * 784;
    if (mode == 1) {
        for (int t = tid; t < 784; t += 64) {
            int p = t >> 4, ic = t & 15;
            int y = p / 7, x = p % 7;
            patch[ic * 144 + (y + 1) * 16 + (x + 1)] = pin[t];
        }
    } else {
        const float* pin2 = in2 + (size_t)bg * 784;
        for (int t = tid; t < 784; t += 64) {
            int ic = t / 49, p = t % 49;
            int y = p / 7, x = p % 7;
            patch[ic * 144 + (y + 1) * 16 + (x + 1)] =
                (pin[t] + pin[t + 802816]) + (pin2[t] + pin2[t + 802816]);
        }
    }
    __syncthreads();
    int g = bg & 31;
    const float* wg = w + (size_t)g * 2304 + (size_t)oh * 8 * 144;
    float* po = out + (size_t)bg * 784 + (size_t)oh * 8 * 49;
    if (tid < 49) {
        int y = tid / 7, x = tid % 7;
        int base = (y + 1) * 16 + (x + 1);
        float acc[8];
#pragma unroll
        for (int oc = 0; oc < 8; ++oc) acc[oc] = 0.f;
        for (int ic = 0; ic < 16; ++ic) {
            const float* pr = patch + ic * 144 + base;
            float win[9];
#pragma unroll
            for (int ky = 0; ky < 3; ++ky)
#pragma unroll
                for (int kx = 0; kx < 3; ++kx)
                    win[ky * 3 + kx] = pr[(ky - 1) * 16 + (kx - 1)];
            const float* wi = wg + ic * 9;
#pragma unroll
            for (int oc = 0; oc < 8; ++oc)
#pragma unroll
                for (int kk = 0; kk < 9; ++kk)
                    acc[oc] += win[kk] * wi[oc * 144 + kk];
        }
#pragma unroll
        for (int oc = 0; oc < 8; ++oc) po[oc * 49 + tid] = acc[oc];
    }
}

// ---------------------------------------------------------------------------
// MFMA key projection: per (b,m): D[16e x 64h] = cp[16e x 196p] * E[m][196p x 64h].
__global__ __launch_bounds__(256) void k_kproj2(const float* __restrict__ cpconv,
                                                const u16* __restrict__ EhT,
                                                const u16* __restrict__ ElT,
                                                u16* __restrict__ Kh,
                                                u16* __restrict__ Kl,
                                                u16* __restrict__ KhT,
                                                u16* __restrict__ KlT) {
    int blk = blockIdx.x;           // b*32 + m
    int b = blk >> 5, m = blk & 31;
    int wave = threadIdx.x >> 6, lane = threadIdx.x & 63;
    int ht = wave;                  // h-tile 0..3
    int n = lane & 15, quad = lane >> 4;

    const float* arow = cpconv + ((size_t)b * 512 + (size_t)n * 32 + m) * 196;
    const u16* bhrow = EhT + ((size_t)m * 64 + ht * 16 + n) * 224;
    const u16* blrow = ElT + ((size_t)m * 64 + ht * 16 + n) * 224;

    floatx4 c = {0.f, 0.f, 0.f, 0.f};
#pragma unroll
    for (int pc = 0; pc < 7; ++pc) {
        int p0 = pc * 32 + quad * 8;
        float av[8];
        if (p0 <= 188) {
            float4 x = *(const float4*)(arow + p0);
            float4 y = *(const float4*)(arow + p0 + 4);
            av[0]=x.x; av[1]=x.y; av[2]=x.z; av[3]=x.w;
            av[4]=y.x; av[5]=y.y; av[6]=y.z; av[7]=y.w;
        } else {
#pragma unroll
            for (int k2 = 0; k2 < 8; ++k2) av[k2] = (p0 + k2 < 196) ? arow[p0 + k2] : 0.f;
        }
        short8 ah, al;
#pragma unroll
        for (int k2 = 0; k2 < 8; ++k2) {
            u16 h = bf16rn(av[k2]);
            ah[k2] = (short)h;
            al[k2] = (short)bf16rn(av[k2] - bf16tof(h));
        }
        short8 bh = ld8(bhrow + pc * 32 + quad * 8);
        short8 bl = ld8(blrow + pc * 32 + quad * 8);
        c = MFMA16(ah, bh, c);
        c = MFMA16(ah, bl, c);
        c = MFMA16(al, bh, c);
    }
    int i = m * 64 + ht * 16 + n;
    size_t bK = (size_t)b * 2112;
    size_t bT = (size_t)b * 33792;
    u16 h[4], l[4];
#pragma unroll
    for (int r = 0; r < 4; ++r) {
        h[r] = bf16rn(c[r]);
        l[r] = bf16rn(c[r] - bf16tof(h[r]));
    }
    *(uint2*)(Kh + (bK + i) * 16 + quad * 4) =
        make_uint2((unsigned)h[0] | ((unsigned)h[1] << 16), (unsigned)h[2] | ((unsigned)h[3] << 16));
    *(uint2*)(Kl + (bK + i) * 16 + quad * 4) =
        make_uint2((unsigned)l[0] | ((unsigned)l[1] << 16), (unsigned)l[2] | ((unsigned)l[3] << 16));
#pragma unroll
    for (int r = 0; r < 4; ++r) {
        KhT[bT + (size_t)(quad * 4 + r) * 2112 + i] = h[r];
        KlT[bT + (size_t)(quad * 4 + r) * 2112 + i] = l[r];
    }
}

// ---------------------------------------------------------------------------
// Q conversion (x0.25, hi/lo bf16).
__global__ __launch_bounds__(256) void k_cvt(const float* __restrict__ qconv,
                                             u16* __restrict__ Qp) {
    int gid = blockIdx.x * 256 + threadIdx.x;
    const float4* q4 = (const float4*)(qconv + (size_t)gid * 16);
    float4 t0 = q4[0], t1 = q4[1], t2 = q4[2], t3 = q4[3];
    float v[16] = {t0.x,t0.y,t0.z,t0.w, t1.x,t1.y,t1.z,t1.w,
                   t2.x,t2.y,t2.z,t2.w, t3.x,t3.y,t3.z,t3.w};
    unsigned hw[8], lw[8];
#pragma unroll
    for (int t = 0; t < 8; ++t) {
        float x0 = v[2*t] * 0.25f, x1 = v[2*t+1] * 0.25f;
        u16 h0 = bf16rn(x0), h1 = bf16rn(x1);
        u16 l0 = bf16rn(x0 - bf16tof(h0)), l1 = bf16rn(x1 - bf16tof(h1));
        hw[t] = (unsigned)h0 | ((unsigned)h1 << 16);
        lw[t] = (unsigned)l0 | ((unsigned)l1 << 16);
    }
    uint4* r4 = (uint4*)(Qp + (size_t)gid * 32);
    r4[0] = make_uint4(hw[0], hw[1], hw[2], hw[3]);
    r4[1] = make_uint4(hw[4], hw[5], hw[6], hw[7]);
    r4[2] = make_uint4(lw[0], lw[1], lw[2], lw[3]);
    r4[3] = make_uint4(lw[4], lw[5], lw[6], lw[7]);
}

// ---------------------------------------------------------------------------
// Column denominators: barrier-free, K frags in registers, Q streamed from L2.
__global__ __launch_bounds__(256) void k_stats4(const u16* __restrict__ Qp,
                                                const u16* __restrict__ Kh,
                                                const u16* __restrict__ Kl,
                                                float* __restrict__ dpart) {
    int blk = blockIdx.x;                   // b*34 + jh*17 + tb
    int b = blk / 34; int rem = blk % 34; int jh = rem / 17; int tb = rem % 17;
    int wave = threadIdx.x >> 6, lane = threadIdx.x & 63;
    int it2 = tb * 4 + wave;                // i-pair 0..67
    if (it2 >= 66) return;
    int ibase = it2 * 32;
    int n = lane & 15, quad = lane >> 4;
    size_t bK = (size_t)b * 2112;
    const u16* kb = Kh + (bK + ibase + n) * 16 + (quad & 1) * 8;
    const u16* lb = Kl + (bK + ibase + n) * 16 + (quad & 1) * 8;
    short8 bh0 = ld8(kb), bh1 = ld8(kb + 256);
    short8 bl0 = ld8(lb), bl1 = ld8(lb + 256);
    const u16* qb = Qp + (size_t)b * 50176 + (size_t)jh * 49 * 512 + n * 32 + quad * 8;
    floatx4 d0 = {0.f,0.f,0.f,0.f}, d1 = {0.f,0.f,0.f,0.f};
    short8 a0 = ld8(qb), a1 = ld8(qb + 512);
    for (int c = 0; c < 49; ++c) {
        short8 a2 = (c + 2 < 49) ? ld8(qb + (size_t)(c + 2) * 512) : a0;
        floatx4 s0 = {0.f,0.f,0.f,0.f}, s1 = {0.f,0.f,0.f,0.f};
        s0 = MFMA16(a0, bh0, s0);
        s0 = MFMA16(a0, bl0, s0);
        s1 = MFMA16(a0, bh1, s1);
        s1 = MFMA16(a0, bl1, s1);
        d0.x += __expf(s0.x); d0.y += __expf(s0.y);
        d0.z += __expf(s0.z); d0.w += __expf(s0.w);
        d1.x += __expf(s1.x); d1.y += __expf(s1.y);
        d1.z += __expf(s1.z); d1.w += __expf(s1.w);
        a0 = a1; a1 = a2;
    }
    float t0 = d0.x + d0.y + d0.z + d0.w;
    float t1 = d1.x + d1.y + d1.z + d1.w;
    t0 += __shfl_xor(t0, 16); t0 += __shfl_xor(t0, 32);
    t1 += __shfl_xor(t1, 16); t1 += __shfl_xor(t1, 32);
    if (quad == 0) {
        dpart[(size_t)jh * 67584 + bK + ibase + n]      = t0;
        dpart[(size_t)jh * 67584 + bK + ibase + 16 + n] = t1;
    }
}

// ---------------------------------------------------------------------------
// Scale V rows by 1/denom in place: Vt[e][i] = (KhT+KlT)[e][i] / d[i], hi/lo split.
__global__ __launch_bounds__(256) void k_vscale(const float* __restrict__ dpart,
                                                u16* __restrict__ VhT,
                                                u16* __restrict__ VlT) {
    int gid = blockIdx.x * 256 + threadIdx.x;     // 135168 total
    int ic = gid % 264;                           // i-chunk of 8
    int be = gid / 264;                           // b*16 + e
    int b = be >> 4, e = be & 15;
    size_t off = (size_t)b * 33792 + (size_t)e * 2112 + (size_t)ic * 8;
    short8 h8 = ld8(VhT + off);
    short8 l8 = ld8(VlT + off);
    const float* dp = dpart + (size_t)b * 2112 + ic * 8;
    float4 da0 = *(const float4*)dp;
    float4 da1 = *(const float4*)(dp + 4);
    float4 db0 = *(const float4*)(dp + 67584);
    float4 db1 = *(const float4*)(dp + 67588);
    float d[8] = {da0.x+db0.x, da0.y+db0.y, da0.z+db0.z, da0.w+db0.w,
                  da1.x+db1.x, da1.y+db1.y, da1.z+db1.z, da1.w+db1.w};
    short8 oh, ol;
#pragma unroll
    for (int k = 0; k < 8; ++k) {
        float v = bf16tof((u16)h8[k]) + bf16tof((u16)l8[k]);
        float sv = v / d[k];
        u16 hh = bf16rn(sv);
        ol[k] = (short)bf16rn(sv - bf16tof(hh));
        oh[k] = (short)hh;
    }
    *(short8*)(VhT + off) = oh;
    *(short8*)(VlT + off) = ol;
}

// ---------------------------------------------------------------------------
// PV v8: pv6 core (swapped QK^T + permlane W transpose, 1/d pre-folded into V,
// 2 j-tiles per wave) with i-split x4 for occupancy (grid 1664).
__global__ __launch_bounds__(256) void k_pv8(const u16* __restrict__ Qp,
                                             const u16* __restrict__ Kh,
                                             const u16* __restrict__ Kl,
                                             const u16* __restrict__ VhT,
                                             const u16* __restrict__ VlT,
                                             float* __restrict__ opart) {
    __shared__ __align__(16) u16 sH[2][32][16];       // [buf][i][e]  (K hi rows)
    __shared__ __align__(16) u16 sL[2][32][16];       // [buf][i][e]  (K lo rows)
    __shared__ __align__(16) u16 tH[2][16][32];       // [buf][e][i]  (Vt hi)
    __shared__ __align__(16) u16 tL[2][16][32];       // [buf][e][i]  (Vt lo)

    int blk = blockIdx.x;                  // b*52 + jtb*4 + iq
    int b = blk / 52; int rem = blk % 52; int jtb = rem >> 2; int iq = rem & 3;
    int tid = threadIdx.x, wave = tid >> 6, lane = tid & 63;
    int n = lane & 15, quad = lane >> 4, qh = quad & 1;
    int jt0 = (jtb * 4 + wave) * 2;        // 2 j-tiles per wave
    int jc0 = jt0     < 98 ? jt0     : 97;
    int jc1 = jt0 + 1 < 98 ? jt0 + 1 : 97;
    int nc = (iq < 2) ? 17 : 16;           // chunks of 32 i-rows
    int i0 = iq * 512 + (iq < 2 ? iq : 2) * 32;   // 0,544,1088,1600
    size_t bK = (size_t)b * 2112;
    size_t bT = (size_t)b * 33792;

    short8 aq0 = ld8(Qp + ((size_t)b * 1568 + (size_t)jc0 * 16 + n) * 32 + quad * 8);
    short8 aq1 = ld8(Qp + ((size_t)b * 1568 + (size_t)jc1 * 16 + n) * 32 + quad * 8);

    int role = wave, L = lane;
    uint4 sreg;
    auto ldchunk = [&](int c) {
        int i0c = i0 + c * 32;
        if (role == 0)      sreg = *(const uint4*)(Kh  + (bK + i0c + (L >> 1)) * 16 + (L & 1) * 8);
        else if (role == 1) sreg = *(const uint4*)(Kl  + (bK + i0c + (L >> 1)) * 16 + (L & 1) * 8);
        else if (role == 2) sreg = *(const uint4*)(VhT + bT + (size_t)(L >> 2) * 2112 + i0c + (L & 3) * 8);
        else                sreg = *(const uint4*)(VlT + bT + (size_t)(L >> 2) * 2112 + i0c + (L & 3) * 8);
    };
    auto stchunk = [&](int bf) {
        if (role == 0)      *(uint4*)(&sH[bf][L >> 1][(L & 1) * 8]) = sreg;
        else if (role == 1) *(uint4*)(&sL[bf][L >> 1][(L & 1) * 8]) = sreg;
        else if (role == 2) *(uint4*)(&tH[bf][L >> 2][(L & 3) * 8]) = sreg;
        else                *(uint4*)(&tL[bf][L >> 2][(L & 3) * 8]) = sreg;
    };

    floatx4 o0 = {0.f, 0.f, 0.f, 0.f}, o1 = {0.f, 0.f, 0.f, 0.f};

    ldchunk(0); stchunk(0); ldchunk(1);
    __syncthreads();
    for (int c = 0; c < nc; ++c) {
        int cb = c & 1;
        short8 sh0 = ld8(&sH[cb][n][qh * 8]);        // K hi, i-local 0..15 (row n)
        short8 sh1 = ld8(&sH[cb][16 + n][qh * 8]);   // K hi, i-local 16..31
        short8 sl0 = ld8(&sL[cb][n][qh * 8]);
        short8 sl1 = ld8(&sL[cb][16 + n][qh * 8]);
        short8 th  = ld8(&tH[cb][n][quad * 8]);      // Vt hi  B-operand
        short8 tl  = ld8(&tL[cb][n][quad * 8]);

        // ---- j-tile 0: sT = K * Q  -> lane holds sT[i=quad*4+r][j=n]
        {
            floatx4 s0 = {0.f,0.f,0.f,0.f}, s1 = {0.f,0.f,0.f,0.f};
            s0 = MFMA16(sh0, aq0, s0);
            s0 = MFMA16(sl0, aq0, s0);
            s1 = MFMA16(sh1, aq0, s1);
            s1 = MFMA16(sl1, aq0, s1);
            unsigned u00 = pack2(__expf(s0[0]), __expf(s0[1]));  // P(2q)
            unsigned u01 = pack2(__expf(s0[2]), __expf(s0[3]));  // P(2q+1)
            unsigned u10 = pack2(__expf(s1[0]), __expf(s1[1]));  // P(8+2q)
            unsigned u11 = pack2(__expf(s1[2]), __expf(s1[3]));  // P(9+2q)
            asm("v_permlane32_swap_b32 %0, %1" : "+v"(u00), "+v"(u10));
            asm("v_permlane32_swap_b32 %0, %1" : "+v"(u01), "+v"(u11));
            asm("v_permlane16_swap_b32 %0, %1" : "+v"(u00), "+v"(u10));
            asm("v_permlane16_swap_b32 %0, %1" : "+v"(u01), "+v"(u11));
            uintx4 uv = {u00, u01, u10, u11};        // W[j=n][i=8q..8q+7]
            short8 aw = __builtin_bit_cast(short8, uv);
            o0 = MFMA16(aw, th, o0);
            o0 = MFMA16(aw, tl, o0);
        }
        // ---- j-tile 1
        {
            floatx4 s0 = {0.f,0.f,0.f,0.f}, s1 = {0.f,0.f,0.f,0.f};
            s0 = MFMA16(sh0, aq1, s0);
            s0 = MFMA16(sl0, aq1, s0);
            s1 = MFMA16(sh1, aq1, s1);
            s1 = MFMA16(sl1, aq1, s1);
            unsigned u00 = pack2(__expf(s0[0]), __expf(s0[1]));
            unsigned u01 = pack2(__expf(s0[2]), __expf(s0[3]));
            unsigned u10 = pack2(__expf(s1[0]), __expf(s1[1]));
            unsigned u11 = pack2(__expf(s1[2]), __expf(s1[3]));
            asm("v_permlane32_swap_b32 %0, %1" : "+v"(u00), "+v"(u10));
            asm("v_permlane32_swap_b32 %0, %1" : "+v"(u01), "+v"(u11));
            asm("v_permlane16_swap_b32 %0, %1" : "+v"(u00), "+v"(u10));
            asm("v_permlane16_swap_b32 %0, %1" : "+v"(u01), "+v"(u11));
            uintx4 uv = {u00, u01, u10, u11};
            short8 aw = __builtin_bit_cast(short8, uv);
            o1 = MFMA16(aw, th, o1);
            o1 = MFMA16(aw, tl, o1);
        }
        if (c + 1 < nc) stchunk((c + 1) & 1);
        if (c + 2 < nc) ldchunk(c + 2);
        __syncthreads();
    }
    if (jt0 < 98) {
        float* ob = opart + (size_t)iq * 802816 +
                    ((size_t)b * 1568 + (size_t)jt0 * 16) * 16;
#pragma unroll
        for (int r = 0; r < 4; ++r) ob[(quad * 4 + r) * 16 + n] = o0[r];
    }
    if (jt0 + 1 < 98) {
        float* ob = opart + (size_t)iq * 802816 +
                    ((size_t)b * 1568 + (size_t)(jt0 + 1) * 16) * 16;
#pragma unroll
        for (int r = 0; r < 4; ++r) ob[(quad * 4 + r) * 16 + n] = o1[r];
    }
}

// ---------------------------------------------------------------------------
// LayerNorm over consecutive groups of 16 floats.
__global__ __launch_bounds__(256) void k_ln(const float* __restrict__ x,
                                            const float* __restrict__ gamma,
                                            const float* __restrict__ beta,
                                            float* __restrict__ out, int ngroups) {
    int g = blockIdx.x * 256 + threadIdx.x;
    if (g >= ngroups) return;
    const float4* xp = (const float4*)(x + (size_t)g * 16);
    float4 x0 = xp[0], x1 = xp[1], x2 = xp[2], x3 = xp[3];
    float sum = x0.x + x0.y + x0.z + x0.w + x1.x + x1.y + x1.z + x1.w
              + x2.x + x2.y + x2.z + x2.w + x3.x + x3.y + x3.z + x3.w;
    float mu = sum * 0.0625f;
    float var = 0.f;
    var += (x0.x-mu)*(x0.x-mu) + (x0.y-mu)*(x0.y-mu) + (x0.z-mu)*(x0.z-mu) + (x0.w-mu)*(x0.w-mu);
    var += (x1.x-mu)*(x1.x-mu) + (x1.y-mu)*(x1.y-mu) + (x1.z-mu)*(x1.z-mu) + (x1.w-mu)*(x1.w-mu);
    var += (x2.x-mu)*(x2.x-mu) + (x2.y-mu)*(x2.y-mu) + (x2.z-mu)*(x2.z-mu) + (x2.w-mu)*(x2.w-mu);
    var += (x3.x-mu)*(x3.x-mu) + (x3.y-mu)*(x3.y-mu) + (x3.z-mu)*(x3.z-mu) + (x3.w-mu)*(x3.w-mu);
    float rstd = rsqrtf(var * 0.0625f + 1e-5f);
    const float4* gp = (const float4*)gamma;
    const float4* bp = (const float4*)beta;
    float4 g0 = gp[0], g1 = gp[1], g2 = gp[2], g3 = gp[3];
    float4 be0 = bp[0], be1 = bp[1], be2 = bp[2], be3 = bp[3];
    float4 o0, o1, o2, o3;
    o0.x = (x0.x-mu)*rstd*g0.x + be0.x; o0.y = (x0.y-mu)*rstd*g0.y + be0.y;
    o0.z = (x0.z-mu)*rstd*g0.z + be0.z; o0.w = (x0.w-mu)*rstd*g0.w + be0.w;
    o1.x = (x1.x-mu)*rstd*g1.x + be1.x; o1.y = (x1.y-mu)*rstd*g1.y + be1.y;
    o1.z = (x1.z-mu)*rstd*g1.z + be1.z; o1.w = (x1.w-mu)*rstd*g1.w + be1.w;
    o2.x = (x2.x-mu)*rstd*g2.x + be2.x; o2.y = (x2.y-mu)*rstd*g2.y + be2.y;
    o2.z = (x2.z-mu)*rstd*g2.z + be2.z; o2.w = (x2.w-mu)*rstd*g2.w + be2.w;
    o3.x = (x3.x-mu)*rstd*g3.x + be3.x; o3.y = (x3.y-mu)*rstd*g3.y + be3.y;
    o3.z = (x3.z-mu)*rstd*g3.z + be3.z; o3.w = (x3.w-mu)*rstd*g3.w + be3.w;
    float4* op = (float4*)(out + (size_t)g * 16);
    op[0] = o0; op[1] = o1; op[2] = o2; op[3] = o3;
}

// ---------------------------------------------------------------------------
extern "C" void kernel_launch(void* const* d_in, const int* in_sizes, int n_in,
                              void* d_out, int out_size, void* d_ws, size_t ws_size,
                              hipStream_t stream) {
    const float* current_pose = (const float*)d_in[0];
    const float* next_pose    = (const float*)d_in[1];
    const float* current_w    = (const float*)d_in[2];
    const float* next_w       = (const float*)d_in[3];
    const float* E_proj       = (const float*)d_in[4];
    const float* rel          = (const float*)d_in[5];
    const float* ln_gamma     = (const float*)d_in[6];
    const float* ln_beta      = (const float*)d_in[7];
    float* out = (float*)d_out;
    float* ws  = (float*)d_ws;

    // workspace (floats):
    //   ws[0 .. 3,211,264): cpconv (conv14 out, read by kproj2), then reused
    //                       as opart (4 x 802,816 partials from pv8)
    //   ws[3,211,264 .. 4,014,080): qconv (read by k_cvt), then dpart
    //                       (stats4 out, read by vscale), then conv2 (read by ln)
    float* cpconv = ws;                 // 3,211,264
    float* opart  = ws;                 // alias (written by pv8 after vscale)
    float* qconv  = ws + 3211264;       //   802,816
    float* dpart  = qconv;              // alias: 2 x 67,584 (after k_cvt)
    float* conv2  = qconv;              // alias (after pv8/vscale; dpart dead)
    float* w2     = ws + 4014080;       //    73,728 -> ends 4,087,808
    u16*   ub     = (u16*)(ws + 4087808);
    u16* Qp  = ub;                      // 1,605,632
    u16* Kh  = ub + 1605632;            // 1,081,344
    u16* Kl  = ub + 2686976;
    u16* KhT = ub + 3768320;            // scaled in place to Vt hi by k_vscale
    u16* KlT = ub + 4849664;            // scaled in place to Vt lo
    u16* EhT = ub + 5931008;            // 458,752
    u16* ElT = ub + 6389760;            // ends 6,848,512 (~30.1 MB total)

    k_ecvt2 <<<72,   256, 0, stream>>>(E_proj, rel, current_w, EhT, ElT,
                                       Kh, Kl, KhT, KlT, w2);
    k_conv14<<<2048, 256, 0, stream>>>(current_pose, w2, cpconv);
    k_conv7 <<<2048, 64,  0, stream>>>(next_pose, next_pose, next_w, qconv, 1);
    k_cvt   <<<196,  256, 0, stream>>>(qconv, Qp);
    k_kproj2<<<1024, 256, 0, stream>>>(cpconv, EhT, ElT, Kh, Kl, KhT, KlT);
    k_stats4<<<1088, 256, 0, stream>>>(Qp, Kh, Kl, dpart);
    k_vscale<<<528,  256, 0, stream>>>(dpart, KhT, KlT);
    k_pv8   <<<1664, 256, 0, stream>>>(Qp, Kh, Kl, KhT, KlT, opart);
    k_conv7 <<<2048, 64,  0, stream>>>(opart, opart + 1605632, next_w, conv2, 0);
    k_ln    <<<196,  256, 0, stream>>>(conv2, ln_gamma, ln_beta, out, 50176);
}